// Round 10
// baseline (101.915 us; speedup 1.0000x reference)
//
#include <hip/hip_runtime.h>
#include <hip/hip_fp16.h>

#define INPUT_SIZE 128
#define NUM_REL 16

typedef int   i32x4 __attribute__((ext_vector_type(4)));
typedef float f32x4 __attribute__((ext_vector_type(4)));

// ---------------------------------------------------------------------------
// R2's kernel 1, verbatim: per-node logit table, fp16, L[n][32].
//   L[n][r]    = x[n] . att_weight[0:128, r]      (r = 0..15, src half)
//   L[n][16+r] = x[n] . att_weight[128:256, r]    (dst half)
// 256 threads = 128 nodes/block, 4 nodes x 4 rels per thread.
// DIAGNOSTIC ROUND: launched TWICE (idempotent) to expose its duration in
// total time: T = 2*k1 + 3*k2;  with R2: k1 + k2 = 43.6 us.
// ---------------------------------------------------------------------------
__global__ __launch_bounds__(256) void node_logits_kernel(
    const float* __restrict__ x,
    const float* __restrict__ w,     // (256,16) row-major
    __half* __restrict__ L,          // (num_nodes, 32) fp16
    int num_nodes)
{
    __shared__ float swc[128 * 32];  // swc[k*32 + r], 16 KB

    const int tid = threadIdx.x;

    #pragma unroll
    for (int i = 0; i < 16; ++i) {
        const int idx = i * 256 + tid;        // 0..4095
        const int k = idx >> 5, r = idx & 31;
        swc[idx] = (r < 16) ? w[k * NUM_REL + r]
                            : w[(INPUT_SIZE + k) * NUM_REL + (r - 16)];
    }
    __syncthreads();

    const int ng = tid >> 3;                  // node group 0..31
    const int rg = tid & 7;                   // rel group  0..7
    const int node0 = blockIdx.x * 128 + ng * 4;
    const int r0 = rg * 4;

    const f32x4* xr[4];
    bool valid[4];
    #pragma unroll
    for (int n = 0; n < 4; ++n) {
        const int nn = node0 + n;
        valid[n] = (nn < num_nodes);
        xr[n] = (const f32x4*)(x + (size_t)(valid[n] ? nn : 0) * INPUT_SIZE);
    }

    float acc[4][4] = {};

    #pragma unroll 4
    for (int ks = 0; ks < 32; ++ks) {         // 4 k's per step
        f32x4 xv[4], wv[4];
        #pragma unroll
        for (int n = 0; n < 4; ++n) xv[n] = xr[n][ks];
        #pragma unroll
        for (int kk = 0; kk < 4; ++kk)
            wv[kk] = *(const f32x4*)&swc[(ks * 4 + kk) * 32 + r0];

        #pragma unroll
        for (int n = 0; n < 4; ++n) {
            #pragma unroll
            for (int c = 0; c < 4; ++c) {
                acc[n][0] += xv[n][c] * wv[c][0];
                acc[n][1] += xv[n][c] * wv[c][1];
                acc[n][2] += xv[n][c] * wv[c][2];
                acc[n][3] += xv[n][c] * wv[c][3];
            }
        }
    }

    #pragma unroll
    for (int n = 0; n < 4; ++n) {
        if (!valid[n]) continue;
        union { __half2 h2[2]; uint2 u; } pk;
        pk.h2[0] = __floats2half2_rn(acc[n][0], acc[n][1]);
        pk.h2[1] = __floats2half2_rn(acc[n][2], acc[n][3]);
        *(uint2*)(L + (size_t)(node0 + n) * 32 + r0) = pk.u;   // 8B aligned
    }
}

// ---------------------------------------------------------------------------
// R2's kernel 2, verbatim: 8 edges/thread, fp16 table gathers, plain
// loads/stores. DIAGNOSTIC: launched THREE times (idempotent).
// ---------------------------------------------------------------------------
__global__ __launch_bounds__(256) void edge_score_kernel(
    const int* __restrict__ ei,      // (2, E) int32
    const int* __restrict__ et,      // (E,) int32
    const __half* __restrict__ L,    // (N, 32) fp16
    float* __restrict__ out,
    int num_edges)
{
    const int i = blockIdx.x * blockDim.x + threadIdx.x;   // octet index
    if (i * 8 >= num_edges) return;

    const i32x4* eis = (const i32x4*)ei;
    const i32x4* eid = (const i32x4*)(ei + num_edges);
    const i32x4* ett = (const i32x4*)et;

    const i32x4 sa = eis[2 * i], sb = eis[2 * i + 1];
    const i32x4 da = eid[2 * i], db = eid[2 * i + 1];
    const i32x4 ta = ett[2 * i], tb = ett[2 * i + 1];

    int s[8], d[8], t[8];
    #pragma unroll
    for (int j = 0; j < 4; ++j) {
        s[j] = sa[j]; s[4 + j] = sb[j];
        d[j] = da[j]; d[4 + j] = db[j];
        t[j] = ta[j]; t[4 + j] = tb[j];
    }

    __half hs[8], hd[8];
    #pragma unroll
    for (int j = 0; j < 8; ++j) hs[j] = L[(size_t)s[j] * 32 + t[j]];
    #pragma unroll
    for (int j = 0; j < 8; ++j) hd[j] = L[(size_t)d[j] * 32 + 16 + t[j]];

    f32x4 r[2];
    #pragma unroll
    for (int j = 0; j < 8; ++j) {
        const float sc = __half2float(hs[j]) + __half2float(hd[j]);
        const float att = 1.f / (1.f + __expf(-sc));
        r[j >> 2][j & 3] = fminf(fmaxf(att, 1e-5f), 0.99999f);
    }
    f32x4* o = (f32x4*)out;
    o[2 * i]     = r[0];
    o[2 * i + 1] = r[1];
}

// Fallback: direct per-edge dot product in f32 (no workspace).
__global__ void edge_direct_kernel(const float* __restrict__ x,
                                   const float* __restrict__ w,
                                   const int* __restrict__ ei,
                                   const int* __restrict__ et,
                                   float* __restrict__ out,
                                   int num_edges) {
    const int e = blockIdx.x * blockDim.x + threadIdx.x;
    if (e >= num_edges) return;
    const int s = ei[e];
    const int d = ei[num_edges + e];
    const int t = et[e];
    const float* xs = x + (size_t)s * INPUT_SIZE;
    const float* xd = x + (size_t)d * INPUT_SIZE;
    float acc = 0.f;
    #pragma unroll 4
    for (int k = 0; k < INPUT_SIZE; ++k)
        acc += xs[k] * w[k * NUM_REL + t] + xd[k] * w[(INPUT_SIZE + k) * NUM_REL + t];
    const float att = 1.f / (1.f + __expf(-acc));
    out[e] = fminf(fmaxf(att, 1e-5f), 0.99999f);
}

extern "C" void kernel_launch(void* const* d_in, const int* in_sizes, int n_in,
                              void* d_out, int out_size, void* d_ws, size_t ws_size,
                              hipStream_t stream) {
    const float* x  = (const float*)d_in[0];   // (50000, 128) f32
    const float* w  = (const float*)d_in[1];   // (256, 16) f32
    const int*   ei = (const int*)d_in[2];     // (2, E) int32
    const int*   et = (const int*)d_in[3];     // (E,) int32
    float* out = (float*)d_out;

    const int num_nodes = in_sizes[0] / INPUT_SIZE;
    const int num_edges = in_sizes[3];

    const size_t ws_needed = (size_t)num_nodes * 32 * sizeof(__half);

    if (ws_size >= ws_needed && (num_edges & 7) == 0) {
        __half* L = (__half*)d_ws;

        const int blocks1 = (num_nodes + 127) / 128;
        const int octs    = num_edges / 8;
        const int blocks2 = (octs + 255) / 256;

        // DIAGNOSTIC REPLICATION (deterministic, idempotent):
        // T = 2*k1 + 3*k2  ->  k2 = T - 2*43.6, k1 = 43.6 - k2.
        node_logits_kernel<<<blocks1, 256, 0, stream>>>(x, w, L, num_nodes);
        node_logits_kernel<<<blocks1, 256, 0, stream>>>(x, w, L, num_nodes);
        edge_score_kernel<<<blocks2, 256, 0, stream>>>(ei, et, L, out, num_edges);
        edge_score_kernel<<<blocks2, 256, 0, stream>>>(ei, et, L, out, num_edges);
        edge_score_kernel<<<blocks2, 256, 0, stream>>>(ei, et, L, out, num_edges);
    } else {
        const int blocks = (num_edges + 255) / 256;
        edge_direct_kernel<<<blocks, 256, 0, stream>>>(x, w, ei, et, out, num_edges);
    }
}

// Round 11
// 36.421 us; speedup vs baseline: 2.7983x; 2.7983x over previous
//
#include <hip/hip_runtime.h>
#include <hip/hip_fp16.h>

#define INPUT_SIZE 128
#define NUM_REL 16

typedef int      i32x4  __attribute__((ext_vector_type(4)));
typedef float    f32x4  __attribute__((ext_vector_type(4)));
typedef _Float16 f16x8  __attribute__((ext_vector_type(8)));

// ---------------------------------------------------------------------------
// Kernel 1 (MFMA rewrite): L[n][0:16) = x[n].w_src, L[n][16:32) = x[n].w_dst
// as a 50000x128 @ 128x32 GEMM via mfma_f32_16x16x32_f16.
// Block = 256 thr = 4 waves; each wave owns one 16-node tile (64 nodes/block).
// Fragment layouts (m89-verified C/D; standard gfx950 A/B):
//   A: lane l holds row=l&15,  k = (l>>4)*8 + e   (e=0..7)
//   B: lane l holds col=l&15,  k = (l>>4)*8 + e
//   D: lane l holds col=l&15,  row=(l>>4)*4 + q   (q=0..3)
// B-frags built from w directly (L2-hot, once per block). No LDS, no barrier.
// ---------------------------------------------------------------------------
__global__ __launch_bounds__(256) void node_logits_mfma(
    const float* __restrict__ x,
    const float* __restrict__ w,     // (256,16) row-major
    __half* __restrict__ L,          // (num_nodes, 32) fp16
    int num_nodes)
{
    const int wave = threadIdx.x >> 6;
    const int lane = threadIdx.x & 63;
    const int m0 = (blockIdx.x * 4 + wave) * 16;
    if (m0 >= num_nodes) return;

    const int ln = lane & 15;        // A-row / B-col / D-col
    const int kg = lane >> 4;        // k-group 0..3

    // B fragments: bfrag[t][ks], t=0 src half, t=1 dst half.
    f16x8 bfrag[2][4];
    #pragma unroll
    for (int t = 0; t < 2; ++t)
        #pragma unroll
        for (int ks = 0; ks < 4; ++ks)
            #pragma unroll
            for (int e = 0; e < 8; ++e) {
                const int k = ks * 32 + kg * 8 + e;
                const float v = (t == 0) ? w[k * NUM_REL + ln]
                                         : w[(INPUT_SIZE + k) * NUM_REL + ln];
                bfrag[t][ks][e] = (_Float16)v;
            }

    // A fragments: row m0+ln (clamped; stores are predicated).
    const int row = (m0 + ln < num_nodes) ? (m0 + ln) : (num_nodes - 1);
    const float* xr = x + (size_t)row * INPUT_SIZE;
    f16x8 afrag[4];
    #pragma unroll
    for (int ks = 0; ks < 4; ++ks) {
        const f32x4 lo = *(const f32x4*)(xr + ks * 32 + kg * 8);
        const f32x4 hi = *(const f32x4*)(xr + ks * 32 + kg * 8 + 4);
        #pragma unroll
        for (int e = 0; e < 4; ++e) {
            afrag[ks][e]     = (_Float16)lo[e];
            afrag[ks][4 + e] = (_Float16)hi[e];
        }
    }

    f32x4 acc0 = {0.f, 0.f, 0.f, 0.f};
    f32x4 acc1 = {0.f, 0.f, 0.f, 0.f};
    #pragma unroll
    for (int ks = 0; ks < 4; ++ks) {
        acc0 = __builtin_amdgcn_mfma_f32_16x16x32_f16(afrag[ks], bfrag[0][ks], acc0, 0, 0, 0);
        acc1 = __builtin_amdgcn_mfma_f32_16x16x32_f16(afrag[ks], bfrag[1][ks], acc1, 0, 0, 0);
    }

    // Store: node r = m0 + kg*4 + q; rel = ln (acc0) / 16+ln (acc1).
    #pragma unroll
    for (int q = 0; q < 4; ++q) {
        const int r = m0 + kg * 4 + q;
        if (r < num_nodes) {
            L[(size_t)r * 32 + ln]      = __float2half(acc0[q]);
            L[(size_t)r * 32 + 16 + ln] = __float2half(acc1[q]);
        }
    }
}

// ---------------------------------------------------------------------------
// Kernel 2: R2's edge kernel VERBATIM (measured ~13.5 us — near floor).
// 8 edges/thread, fp16 table gathers, plain loads/stores.
// ---------------------------------------------------------------------------
__global__ __launch_bounds__(256) void edge_score_kernel(
    const int* __restrict__ ei,      // (2, E) int32
    const int* __restrict__ et,      // (E,) int32
    const __half* __restrict__ L,    // (N, 32) fp16
    float* __restrict__ out,
    int num_edges)
{
    const int i = blockIdx.x * blockDim.x + threadIdx.x;   // octet index
    if (i * 8 >= num_edges) return;

    const i32x4* eis = (const i32x4*)ei;
    const i32x4* eid = (const i32x4*)(ei + num_edges);
    const i32x4* ett = (const i32x4*)et;

    const i32x4 sa = eis[2 * i], sb = eis[2 * i + 1];
    const i32x4 da = eid[2 * i], db = eid[2 * i + 1];
    const i32x4 ta = ett[2 * i], tb = ett[2 * i + 1];

    int s[8], d[8], t[8];
    #pragma unroll
    for (int j = 0; j < 4; ++j) {
        s[j] = sa[j]; s[4 + j] = sb[j];
        d[j] = da[j]; d[4 + j] = db[j];
        t[j] = ta[j]; t[4 + j] = tb[j];
    }

    __half hs[8], hd[8];
    #pragma unroll
    for (int j = 0; j < 8; ++j) hs[j] = L[(size_t)s[j] * 32 + t[j]];
    #pragma unroll
    for (int j = 0; j < 8; ++j) hd[j] = L[(size_t)d[j] * 32 + 16 + t[j]];

    f32x4 r[2];
    #pragma unroll
    for (int j = 0; j < 8; ++j) {
        const float sc = __half2float(hs[j]) + __half2float(hd[j]);
        const float att = 1.f / (1.f + __expf(-sc));
        r[j >> 2][j & 3] = fminf(fmaxf(att, 1e-5f), 0.99999f);
    }
    f32x4* o = (f32x4*)out;
    o[2 * i]     = r[0];
    o[2 * i + 1] = r[1];
}

// Fallback: direct per-edge dot product in f32 (no workspace).
__global__ void edge_direct_kernel(const float* __restrict__ x,
                                   const float* __restrict__ w,
                                   const int* __restrict__ ei,
                                   const int* __restrict__ et,
                                   float* __restrict__ out,
                                   int num_edges) {
    const int e = blockIdx.x * blockDim.x + threadIdx.x;
    if (e >= num_edges) return;
    const int s = ei[e];
    const int d = ei[num_edges + e];
    const int t = et[e];
    const float* xs = x + (size_t)s * INPUT_SIZE;
    const float* xd = x + (size_t)d * INPUT_SIZE;
    float acc = 0.f;
    #pragma unroll 4
    for (int k = 0; k < INPUT_SIZE; ++k)
        acc += xs[k] * w[k * NUM_REL + t] + xd[k] * w[(INPUT_SIZE + k) * NUM_REL + t];
    const float att = 1.f / (1.f + __expf(-acc));
    out[e] = fminf(fmaxf(att, 1e-5f), 0.99999f);
}

extern "C" void kernel_launch(void* const* d_in, const int* in_sizes, int n_in,
                              void* d_out, int out_size, void* d_ws, size_t ws_size,
                              hipStream_t stream) {
    const float* x  = (const float*)d_in[0];   // (50000, 128) f32
    const float* w  = (const float*)d_in[1];   // (256, 16) f32
    const int*   ei = (const int*)d_in[2];     // (2, E) int32
    const int*   et = (const int*)d_in[3];     // (E,) int32
    float* out = (float*)d_out;

    const int num_nodes = in_sizes[0] / INPUT_SIZE;
    const int num_edges = in_sizes[3];

    const size_t ws_needed = (size_t)num_nodes * 32 * sizeof(__half);

    if (ws_size >= ws_needed && (num_edges & 7) == 0) {
        __half* L = (__half*)d_ws;

        const int blocks1 = (num_nodes + 63) / 64;   // 64 nodes per block
        node_logits_mfma<<<blocks1, 256, 0, stream>>>(x, w, L, num_nodes);

        const int octs    = num_edges / 8;
        const int blocks2 = (octs + 255) / 256;
        edge_score_kernel<<<blocks2, 256, 0, stream>>>(ei, et, L, out, num_edges);
    } else {
        const int blocks = (num_edges + 255) / 256;
        edge_direct_kernel<<<blocks, 256, 0, stream>>>(x, w, ei, et, out, num_edges);
    }
}